// Round 2
// baseline (1632.731 us; speedup 1.0000x reference)
//
#include <hip/hip_runtime.h>

#define N_NODES 100000
#define N_EDGES 500000
#define N_GRAPHS 100
#define DIM 146
#define BN_EPS 1e-5f
#define GS_PART 8
#define GS_STRIDE 147   // 146 cols + 1 count slot

// ---------------- prep kernels ----------------
__global__ void hist_kernel(const int* __restrict__ src, const int* __restrict__ dst,
                            int* __restrict__ deg_out, int* __restrict__ deg_in) {
  int e = blockIdx.x * 256 + threadIdx.x;
  if (e < N_EDGES) {
    atomicAdd(&deg_out[src[e]], 1);
    atomicAdd(&deg_in[dst[e]], 1);
  }
}

__global__ void norm_kernel(const int* __restrict__ deg_out, const int* __restrict__ deg_in,
                            float* __restrict__ norm_out, float* __restrict__ norm_in) {
  int v = blockIdx.x * 256 + threadIdx.x;
  if (v < N_NODES) {
    norm_out[v] = rsqrtf((float)max(deg_out[v], 1));
    norm_in[v]  = rsqrtf((float)max(deg_in[v], 1));
  }
}

__global__ void scan1_kernel(const int* __restrict__ deg_in, int* __restrict__ bsums) {
  __shared__ int sred[256];
  int t0 = blockIdx.x * 1024 + threadIdx.x * 4;
  int s = 0;
#pragma unroll
  for (int i = 0; i < 4; i++) { int v = t0 + i; s += (v < N_NODES) ? deg_in[v] : 0; }
  sred[threadIdx.x] = s; __syncthreads();
  for (int off = 128; off > 0; off >>= 1) {
    if (threadIdx.x < off) sred[threadIdx.x] += sred[threadIdx.x + off];
    __syncthreads();
  }
  if (threadIdx.x == 0) bsums[blockIdx.x] = sred[0];
}

__global__ void scan2_kernel(const int* __restrict__ bsums, int* __restrict__ bofs,
                             int* __restrict__ row_ptr, int nb) {
  if (threadIdx.x == 0 && blockIdx.x == 0) {
    int run = 0;
    for (int i = 0; i < nb; i++) { bofs[i] = run; run += bsums[i]; }
    row_ptr[N_NODES] = run;
  }
}

__global__ void scan3_kernel(const int* __restrict__ deg_in, const int* __restrict__ bofs,
                             int* __restrict__ row_ptr) {
  __shared__ int ssc[256];
  int t0 = blockIdx.x * 1024 + threadIdx.x * 4;
  int v4[4]; int s = 0;
#pragma unroll
  for (int i = 0; i < 4; i++) { int v = t0 + i; v4[i] = (v < N_NODES) ? deg_in[v] : 0; s += v4[i]; }
  ssc[threadIdx.x] = s; __syncthreads();
  for (int off = 1; off < 256; off <<= 1) {
    int t = (threadIdx.x >= off) ? ssc[threadIdx.x - off] : 0;
    __syncthreads();
    ssc[threadIdx.x] += t;
    __syncthreads();
  }
  int ex = ssc[threadIdx.x] - s + bofs[blockIdx.x];
#pragma unroll
  for (int i = 0; i < 4; i++) {
    int v = t0 + i;
    if (v < N_NODES) { row_ptr[v] = ex; ex += v4[i]; }
  }
}

__global__ void csr_fill_kernel(const int* __restrict__ src, const int* __restrict__ dst,
                                const int* __restrict__ row_ptr, int* __restrict__ fill,
                                int* __restrict__ csr) {
  int e = blockIdx.x * 256 + threadIdx.x;
  if (e < N_EDGES) {
    int d = dst[e];
    int slot = atomicAdd(&fill[d], 1);
    csr[row_ptr[d] + slot] = src[e];
  }
}

// ---------------- GEMM: out = A @ W + b  (optionally *snorm, +col stats) ----------------
// No LDS staging: each A-row is read only by one wave (broadcast loads), so
// in-place A==out is safe by wave lockstep. float2 along k for density.
template <bool LAYER>
__global__ __launch_bounds__(256) void gemm_kernel(
    const float* __restrict__ A, const float* __restrict__ W, const float* __restrict__ bias,
    const float* __restrict__ snorm, float* __restrict__ out, float* __restrict__ stats) {
  __shared__ float sred[2 * DIM];
  if (LAYER) {
    for (int i = threadIdx.x; i < 2 * DIM; i += 256) sred[i] = 0.f;
    __syncthreads();
  }
  int tx = threadIdx.x & 31, ty = threadIdx.x >> 5;
  int r0 = blockIdx.x * 64 + ty * 8;
  // precomputed row offsets (clamped so OOB threads read valid memory)
  int rofs[8];
#pragma unroll
  for (int i = 0; i < 8; i++) rofs[i] = min(r0 + i, N_NODES - 1) * DIM;
  int c4 = 128 + min(tx, 17);  // clamped col for j=4 (garbage lanes never stored)

  float acc[8][5];
#pragma unroll
  for (int i = 0; i < 8; i++)
#pragma unroll
    for (int j = 0; j < 5; j++) acc[i][j] = 0.f;

#pragma unroll 2
  for (int k = 0; k < DIM; k += 2) {
    float2 a[8];
#pragma unroll
    for (int i = 0; i < 8; i++) a[i] = *(const float2*)(A + rofs[i] + k);
    const float* Wk = W + k * DIM;
    float w0[5], w1[5];
#pragma unroll
    for (int j = 0; j < 4; j++) {
      w0[j] = Wk[tx + 32 * j];
      w1[j] = Wk[DIM + tx + 32 * j];
    }
    w0[4] = Wk[c4];
    w1[4] = Wk[DIM + c4];
#pragma unroll
    for (int i = 0; i < 8; i++)
#pragma unroll
      for (int j = 0; j < 5; j++) {
        acc[i][j] = fmaf(a[i].x, w0[j], acc[i][j]);
        acc[i][j] = fmaf(a[i].y, w1[j], acc[i][j]);
      }
  }

  float sn[8];
  if (LAYER) {
#pragma unroll
    for (int i = 0; i < 8; i++) sn[i] = snorm[min(r0 + i, N_NODES - 1)];
  }

#pragma unroll
  for (int j = 0; j < 5; j++) {
    int c = tx + 32 * j;
    if (c < DIM) {
      float b = bias[c];
      float ssum = 0.f, ssq = 0.f;
#pragma unroll
      for (int i = 0; i < 8; i++) {
        int r = r0 + i;
        if (r < N_NODES) {
          float val = acc[i][j] + b;
          if (LAYER) val *= sn[i];
          out[(size_t)r * DIM + c] = val;
          if (LAYER) { ssum += val; ssq += val * val; }
        }
      }
      if (LAYER) {
        atomicAdd(&sred[c], ssum);
        atomicAdd(&sred[DIM + c], ssq);
      }
    }
  }
  if (LAYER) {
    __syncthreads();
    for (int i = threadIdx.x; i < 2 * DIM; i += 256) atomicAdd(&stats[i], sred[i]);
  }
}

// ---------------- aggregation: one wave per destination node, float2 gathers ----------------
__global__ __launch_bounds__(256) void agg_kernel(
    const float* __restrict__ h, const int* __restrict__ row_ptr, const int* __restrict__ csr,
    const float* __restrict__ norm_out, const float* __restrict__ norm_in, float* __restrict__ out) {
  int wid = threadIdx.x >> 6, lane = threadIdx.x & 63;
  int v = blockIdx.x * 4 + wid;
  if (v >= N_NODES) return;
  int e0 = row_ptr[v], e1 = row_ptr[v + 1];
  float a0 = 0.f, a1 = 0.f, a2 = 0.f;
  for (int e = e0; e < e1; e++) {
    int s = csr[e];
    float sc = norm_out[s];
    const float* hr = h + (size_t)s * DIM;
    float2 x = *(const float2*)(hr + 2 * lane);
    a0 = fmaf(x.x, sc, a0);
    a1 = fmaf(x.y, sc, a1);
    if (lane < 18) a2 = fmaf(hr[128 + lane], sc, a2);
  }
  float ni = norm_in[v];
  float* ow = out + (size_t)v * DIM;
  float2 r01 = make_float2(a0 * ni, a1 * ni);
  *(float2*)(ow + 2 * lane) = r01;
  if (lane < 18) ow[128 + lane] = a2 * ni;
}

// ---------------- fused BN-prep + BN + ReLU + residual (in-place on h) ----------------
__global__ __launch_bounds__(256) void bn_kernel(const float* __restrict__ tmp,
                                                 const float* __restrict__ stats,
                                                 const float* __restrict__ gamma,
                                                 const float* __restrict__ beta,
                                                 float* __restrict__ h) {
  __shared__ float2 scs[DIM / 2], shs[DIM / 2];
  int t = threadIdx.x;
  if (t < DIM / 2) {
    int c0 = 2 * t, c1 = c0 + 1;
    float mu0 = stats[c0] * (1.f / N_NODES), mu1 = stats[c1] * (1.f / N_NODES);
    float v0 = stats[DIM + c0] * (1.f / N_NODES) - mu0 * mu0;
    float v1 = stats[DIM + c1] * (1.f / N_NODES) - mu1 * mu1;
    float s0 = gamma[c0] * rsqrtf(v0 + BN_EPS), s1 = gamma[c1] * rsqrtf(v1 + BN_EPS);
    scs[t] = make_float2(s0, s1);
    shs[t] = make_float2(beta[c0] - mu0 * s0, beta[c1] - mu1 * s1);
  }
  __syncthreads();
  int idx = blockIdx.x * 256 + t;
  if (idx >= N_NODES * (DIM / 2)) return;
  int v = idx / (DIM / 2), c2 = idx - v * (DIM / 2);
  float2 tv = *(const float2*)(tmp + (size_t)v * DIM + 2 * c2);
  float2 sc = scs[c2], sh = shs[c2];
  float2* hp = (float2*)(h + (size_t)v * DIM + 2 * c2);
  float2 hv = *hp;
  float x0 = fmaf(tv.x, sc.x, sh.x); x0 = fmaxf(x0, 0.f);
  float x1 = fmaf(tv.y, sc.y, sh.y); x1 = fmaxf(x1, 0.f);
  hv.x += x0; hv.y += x1;
  *hp = hv;
}

// ---------------- layer-3 fused: BN+ReLU+residual -> per-graph sum ----------------
// Column-per-thread; register accumulation over 64 rows; ~1 atomic flush/block.
__global__ __launch_bounds__(192) void gsum_kernel(
    const float* __restrict__ tmp, const float* __restrict__ stats,
    const float* __restrict__ gamma, const float* __restrict__ beta,
    const float* __restrict__ h, const int* __restrict__ gids,
    float* __restrict__ hgp) {
  int t = threadIdx.x;
  if (t > DIM) return;  // t==DIM is the count thread; 147..191 idle (no barriers below)
  float sc = 0.f, sh = 0.f;
  if (t < DIM) {
    float mu = stats[t] * (1.f / N_NODES);
    float var = stats[DIM + t] * (1.f / N_NODES) - mu * mu;
    sc = gamma[t] * rsqrtf(var + BN_EPS);
    sh = beta[t] - mu * sc;
  }
  int r0 = blockIdx.x * 64;
  int part = blockIdx.x & (GS_PART - 1);
  float accv = 0.f;
  int g_prev = gids[r0];
  for (int rr = 0; rr < 64; rr++) {
    int r = r0 + rr;
    if (r >= N_NODES) break;
    int g = gids[r];
    if (g != g_prev) {  // uniform branch: all threads read the same gids[r]
      atomicAdd(&hgp[(size_t)(part * N_GRAPHS + g_prev) * GS_STRIDE + t], accv);
      accv = 0.f; g_prev = g;
    }
    float val;
    if (t < DIM) {
      float x = fmaf(tmp[(size_t)r * DIM + t], sc, sh);
      x = fmaxf(x, 0.f);
      val = h[(size_t)r * DIM + t] + x;
    } else {
      val = 1.f;
    }
    accv += val;
  }
  atomicAdd(&hgp[(size_t)(part * N_GRAPHS + g_prev) * GS_STRIDE + t], accv);
}

// ---------------- fused mean + MLP readout: one block per graph ----------------
__global__ __launch_bounds__(256) void mlp_kernel(
    const float* __restrict__ hgp,
    const float* __restrict__ W1, const float* __restrict__ b1,
    const float* __restrict__ W2, const float* __restrict__ b2,
    const float* __restrict__ W3, const float* __restrict__ b3,
    float* __restrict__ out) {
  __shared__ float hrow[DIM];
  __shared__ float x1[73];
  __shared__ float x2[36];
  int g = blockIdx.x;
  int t = threadIdx.x;
  if (t < DIM) {
    float s = 0.f, cnt = 0.f;
#pragma unroll
    for (int p = 0; p < GS_PART; p++) {
      const float* row = hgp + (size_t)(p * N_GRAPHS + g) * GS_STRIDE;
      s += row[t];
      cnt += row[DIM];
    }
    hrow[t] = s / cnt;
  }
  __syncthreads();
  if (t < 73) {
    float s = b1[t];
    for (int k = 0; k < DIM; k++) s = fmaf(hrow[k], W1[k * 73 + t], s);
    x1[t] = s > 0.f ? s : 0.f;
  }
  __syncthreads();
  if (t < 36) {
    float s = b2[t];
    for (int k = 0; k < 73; k++) s = fmaf(x1[k], W2[k * 36 + t], s);
    x2[t] = s > 0.f ? s : 0.f;
  }
  __syncthreads();
  if (t < 10) {
    float s = b3[t];
    for (int k = 0; k < 36; k++) s = fmaf(x2[k], W3[k * 10 + t], s);
    out[g * 10 + t] = s;
  }
}

extern "C" void kernel_launch(void* const* d_in, const int* in_sizes, int n_in,
                              void* d_out, int out_size, void* d_ws, size_t ws_size,
                              hipStream_t stream) {
  const float* nodes_feat = (const float*)d_in[0];
  const float* snorm  = (const float*)d_in[1];
  const float* W_emb  = (const float*)d_in[2];
  const float* b_emb  = (const float*)d_in[3];
  const float* Ws     = (const float*)d_in[4];
  const float* bs     = (const float*)d_in[5];
  const float* gammas = (const float*)d_in[6];
  const float* betas  = (const float*)d_in[7];
  const float* W1 = (const float*)d_in[8];
  const float* b1 = (const float*)d_in[9];
  const float* W2 = (const float*)d_in[10];
  const float* b2 = (const float*)d_in[11];
  const float* W3 = (const float*)d_in[12];
  const float* b3 = (const float*)d_in[13];
  const int* src  = (const int*)d_in[14];
  const int* dst  = (const int*)d_in[15];
  const int* gids = (const int*)d_in[16];
  float* out = (float*)d_out;

  char* base = (char*)d_ws;
  size_t off = 0;
  auto alloc = [&](size_t bytes) { void* p = base + off; off += (bytes + 255) & ~size_t(255); return p; };
  float* h   = (float*)alloc((size_t)N_NODES * DIM * 4);
  float* tmp = (float*)alloc((size_t)N_NODES * DIM * 4);
  char* zstart = base + off;
  int* deg_out = (int*)alloc(N_NODES * 4);
  int* deg_in  = (int*)alloc(N_NODES * 4);
  int* fill    = (int*)alloc(N_NODES * 4);
  float* stats = (float*)alloc(4 * 2 * DIM * 4);   // per layer: [sum, sumsq]
  float* hgp   = (float*)alloc((size_t)GS_PART * N_GRAPHS * GS_STRIDE * 4);
  size_t zbytes = (size_t)((base + off) - zstart);
  int* row_ptr = (int*)alloc((N_NODES + 1) * 4);
  float* norm_out = (float*)alloc(N_NODES * 4);
  float* norm_in  = (float*)alloc(N_NODES * 4);
  int* csr   = (int*)alloc((size_t)N_EDGES * 4);
  int* bsums = (int*)alloc(128 * 4);
  int* bofs  = (int*)alloc(128 * 4);

  hipMemsetAsync(zstart, 0, zbytes, stream);

  hist_kernel<<<(N_EDGES + 255) / 256, 256, 0, stream>>>(src, dst, deg_out, deg_in);
  norm_kernel<<<(N_NODES + 255) / 256, 256, 0, stream>>>(deg_out, deg_in, norm_out, norm_in);
  int nb = (N_NODES + 1023) / 1024;
  scan1_kernel<<<nb, 256, 0, stream>>>(deg_in, bsums);
  scan2_kernel<<<1, 64, 0, stream>>>(bsums, bofs, row_ptr, nb);
  scan3_kernel<<<nb, 256, 0, stream>>>(deg_in, bofs, row_ptr);
  csr_fill_kernel<<<(N_EDGES + 255) / 256, 256, 0, stream>>>(src, dst, row_ptr, fill, csr);

  gemm_kernel<false><<<(N_NODES + 63) / 64, 256, 0, stream>>>(nodes_feat, W_emb, b_emb, nullptr, h, nullptr);

  for (int l = 0; l < 4; l++) {
    float* st = stats + l * 2 * DIM;
    agg_kernel<<<(N_NODES + 3) / 4, 256, 0, stream>>>(h, row_ptr, csr, norm_out, norm_in, tmp);
    gemm_kernel<true><<<(N_NODES + 63) / 64, 256, 0, stream>>>(tmp, Ws + (size_t)l * DIM * DIM,
                                                               bs + l * DIM, snorm, tmp, st);
    if (l < 3) {
      bn_kernel<<<(N_NODES * (DIM / 2) + 255) / 256, 256, 0, stream>>>(
          tmp, st, gammas + l * DIM, betas + l * DIM, h);
    } else {
      gsum_kernel<<<(N_NODES + 63) / 64, 192, 0, stream>>>(
          tmp, st, gammas + l * DIM, betas + l * DIM, h, gids, hgp);
    }
  }

  mlp_kernel<<<N_GRAPHS, 256, 0, stream>>>(hgp, W1, b1, W2, b2, W3, b3, out);
}

// Round 3
// 1379.527 us; speedup vs baseline: 1.1835x; 1.1835x over previous
//
#include <hip/hip_runtime.h>

#define N_NODES 100000
#define N_EDGES 500000
#define N_GRAPHS 100
#define DIM 146
#define WT_STRIDE 152   // padded k-extent of transposed W (multiple of 4, 16B-aligned rows)
#define BN_EPS 1e-5f
#define GS_PART 8
#define GS_STRIDE 147   // 146 cols + 1 count slot

// ---------------- prep kernels ----------------
__global__ void hist_kernel(const int* __restrict__ src, const int* __restrict__ dst,
                            int* __restrict__ deg_out, int* __restrict__ deg_in) {
  int e = blockIdx.x * 256 + threadIdx.x;
  if (e < N_EDGES) {
    atomicAdd(&deg_out[src[e]], 1);
    atomicAdd(&deg_in[dst[e]], 1);
  }
}

__global__ void norm_kernel(const int* __restrict__ deg_out, const int* __restrict__ deg_in,
                            float* __restrict__ norm_out, float* __restrict__ norm_in) {
  int v = blockIdx.x * 256 + threadIdx.x;
  if (v < N_NODES) {
    norm_out[v] = rsqrtf((float)max(deg_out[v], 1));
    norm_in[v]  = rsqrtf((float)max(deg_in[v], 1));
  }
}

__global__ void scan1_kernel(const int* __restrict__ deg_in, int* __restrict__ bsums) {
  __shared__ int sred[256];
  int t0 = blockIdx.x * 1024 + threadIdx.x * 4;
  int s = 0;
#pragma unroll
  for (int i = 0; i < 4; i++) { int v = t0 + i; s += (v < N_NODES) ? deg_in[v] : 0; }
  sred[threadIdx.x] = s; __syncthreads();
  for (int off = 128; off > 0; off >>= 1) {
    if (threadIdx.x < off) sred[threadIdx.x] += sred[threadIdx.x + off];
    __syncthreads();
  }
  if (threadIdx.x == 0) bsums[blockIdx.x] = sred[0];
}

__global__ void scan2_kernel(const int* __restrict__ bsums, int* __restrict__ bofs,
                             int* __restrict__ row_ptr, int nb) {
  if (threadIdx.x == 0 && blockIdx.x == 0) {
    int run = 0;
    for (int i = 0; i < nb; i++) { bofs[i] = run; run += bsums[i]; }
    row_ptr[N_NODES] = run;
  }
}

__global__ void scan3_kernel(const int* __restrict__ deg_in, const int* __restrict__ bofs,
                             int* __restrict__ row_ptr) {
  __shared__ int ssc[256];
  int t0 = blockIdx.x * 1024 + threadIdx.x * 4;
  int v4[4]; int s = 0;
#pragma unroll
  for (int i = 0; i < 4; i++) { int v = t0 + i; v4[i] = (v < N_NODES) ? deg_in[v] : 0; s += v4[i]; }
  ssc[threadIdx.x] = s; __syncthreads();
  for (int off = 1; off < 256; off <<= 1) {
    int t = (threadIdx.x >= off) ? ssc[threadIdx.x - off] : 0;
    __syncthreads();
    ssc[threadIdx.x] += t;
    __syncthreads();
  }
  int ex = ssc[threadIdx.x] - s + bofs[blockIdx.x];
#pragma unroll
  for (int i = 0; i < 4; i++) {
    int v = t0 + i;
    if (v < N_NODES) { row_ptr[v] = ex; ex += v4[i]; }
  }
}

__global__ void csr_fill_kernel(const int* __restrict__ src, const int* __restrict__ dst,
                                const int* __restrict__ row_ptr, int* __restrict__ fill,
                                int* __restrict__ csr) {
  int e = blockIdx.x * 256 + threadIdx.x;
  if (e < N_EDGES) {
    int d = dst[e];
    int slot = atomicAdd(&fill[d], 1);
    csr[row_ptr[d] + slot] = src[e];
  }
}

// ---------------- W transpose: Wt[m][c*WT_STRIDE + k] = W[m][k*DIM + c], zero-padded k ----
__global__ void wtrans_kernel(const float* __restrict__ W_emb, const float* __restrict__ Ws,
                              float* __restrict__ Wt) {
  int m = blockIdx.y;
  const float* W = (m == 0) ? W_emb : Ws + (size_t)(m - 1) * DIM * DIM;
  int idx = blockIdx.x * 256 + threadIdx.x;
  if (idx < DIM * WT_STRIDE) {
    int c = idx / WT_STRIDE, k = idx - c * WT_STRIDE;
    Wt[(size_t)m * DIM * WT_STRIDE + idx] = (k < DIM) ? W[k * DIM + c] : 0.f;
  }
}

// ---------------- GEMM: out = A @ W + b  (optionally *snorm, +col stats) ----------------
// A staged in LDS (stride 148, 16B-aligned rows, zero-padded k to 148) -> ds_read_b128.
// W pre-transposed (Wt[c][k], stride 152) -> float4 loads along k.
// In-place A==out safe: full tile staged before any write.
template <bool LAYER>
__global__ __launch_bounds__(256, 4) void gemm_kernel(
    const float* __restrict__ A, const float* __restrict__ Wt, const float* __restrict__ bias,
    const float* __restrict__ snorm, float* __restrict__ out, float* __restrict__ stats) {
  __shared__ __align__(16) float sA[64 * 148];
  __shared__ float sred[2 * DIM];
  int r0 = blockIdx.x * 64;
  int rows = min(64, N_NODES - r0);
  const float* Ab = A + (size_t)r0 * DIM;
  for (int i = threadIdx.x; i < 64 * 148; i += 256) {
    int r = i / 148, c = i - r * 148;
    sA[i] = (c < DIM && r < rows) ? Ab[(size_t)r * DIM + c] : 0.f;
  }
  if (LAYER) { for (int i = threadIdx.x; i < 2 * DIM; i += 256) sred[i] = 0.f; }
  __syncthreads();

  int tx = threadIdx.x & 31, ty = threadIdx.x >> 5;
  const float* sArow = sA + ty * 8 * 148;
  const float* wp[5];
#pragma unroll
  for (int j = 0; j < 4; j++) wp[j] = Wt + (size_t)(tx + 32 * j) * WT_STRIDE;
  wp[4] = Wt + (size_t)(128 + min(tx, 17)) * WT_STRIDE;

  float acc[8][5];
#pragma unroll
  for (int i = 0; i < 8; i++)
#pragma unroll
    for (int j = 0; j < 5; j++) acc[i][j] = 0.f;

  for (int k = 0; k < 148; k += 4) {
    float4 w[5];
#pragma unroll
    for (int j = 0; j < 5; j++) w[j] = *(const float4*)(wp[j] + k);
    float4 a[8];
#pragma unroll
    for (int i = 0; i < 8; i++) a[i] = *(const float4*)(sArow + i * 148 + k);
#pragma unroll
    for (int i = 0; i < 8; i++)
#pragma unroll
      for (int j = 0; j < 5; j++) {
        acc[i][j] = fmaf(a[i].x, w[j].x, acc[i][j]);
        acc[i][j] = fmaf(a[i].y, w[j].y, acc[i][j]);
        acc[i][j] = fmaf(a[i].z, w[j].z, acc[i][j]);
        acc[i][j] = fmaf(a[i].w, w[j].w, acc[i][j]);
      }
  }

  int rb = r0 + ty * 8;
  float sn[8];
  if (LAYER) {
#pragma unroll
    for (int i = 0; i < 8; i++) sn[i] = snorm[min(rb + i, N_NODES - 1)];
  }

#pragma unroll
  for (int j = 0; j < 5; j++) {
    int c = tx + 32 * j;
    if (c < DIM) {
      float b = bias[c];
      float ssum = 0.f, ssq = 0.f;
#pragma unroll
      for (int i = 0; i < 8; i++) {
        int r = rb + i;
        if (r < N_NODES) {
          float val = acc[i][j] + b;
          if (LAYER) val *= sn[i];
          out[(size_t)r * DIM + c] = val;
          if (LAYER) { ssum += val; ssq += val * val; }
        }
      }
      if (LAYER) {
        atomicAdd(&sred[c], ssum);
        atomicAdd(&sred[DIM + c], ssq);
      }
    }
  }
  if (LAYER) {
    __syncthreads();
    for (int i = threadIdx.x; i < 2 * DIM; i += 256) atomicAdd(&stats[i], sred[i]);
  }
}

// ---------------- aggregation: one wave per destination node, float2 gathers ----------------
__global__ __launch_bounds__(256) void agg_kernel(
    const float* __restrict__ h, const int* __restrict__ row_ptr, const int* __restrict__ csr,
    const float* __restrict__ norm_out, const float* __restrict__ norm_in, float* __restrict__ out) {
  int wid = threadIdx.x >> 6, lane = threadIdx.x & 63;
  int v = blockIdx.x * 4 + wid;
  if (v >= N_NODES) return;
  int e0 = row_ptr[v], e1 = row_ptr[v + 1];
  float a0 = 0.f, a1 = 0.f, a2 = 0.f;
  for (int e = e0; e < e1; e++) {
    int s = csr[e];
    float sc = norm_out[s];
    const float* hr = h + (size_t)s * DIM;
    float2 x = *(const float2*)(hr + 2 * lane);
    a0 = fmaf(x.x, sc, a0);
    a1 = fmaf(x.y, sc, a1);
    if (lane < 18) a2 = fmaf(hr[128 + lane], sc, a2);
  }
  float ni = norm_in[v];
  float* ow = out + (size_t)v * DIM;
  float2 r01 = make_float2(a0 * ni, a1 * ni);
  *(float2*)(ow + 2 * lane) = r01;
  if (lane < 18) ow[128 + lane] = a2 * ni;
}

// ---------------- fused BN-prep + BN + ReLU + residual (in-place on h) ----------------
__global__ __launch_bounds__(256) void bn_kernel(const float* __restrict__ tmp,
                                                 const float* __restrict__ stats,
                                                 const float* __restrict__ gamma,
                                                 const float* __restrict__ beta,
                                                 float* __restrict__ h) {
  __shared__ float2 scs[DIM / 2], shs[DIM / 2];
  int t = threadIdx.x;
  if (t < DIM / 2) {
    int c0 = 2 * t, c1 = c0 + 1;
    float mu0 = stats[c0] * (1.f / N_NODES), mu1 = stats[c1] * (1.f / N_NODES);
    float v0 = stats[DIM + c0] * (1.f / N_NODES) - mu0 * mu0;
    float v1 = stats[DIM + c1] * (1.f / N_NODES) - mu1 * mu1;
    float s0 = gamma[c0] * rsqrtf(v0 + BN_EPS), s1 = gamma[c1] * rsqrtf(v1 + BN_EPS);
    scs[t] = make_float2(s0, s1);
    shs[t] = make_float2(beta[c0] - mu0 * s0, beta[c1] - mu1 * s1);
  }
  __syncthreads();
  int idx = blockIdx.x * 256 + t;
  if (idx >= N_NODES * (DIM / 2)) return;
  int v = idx / (DIM / 2), c2 = idx - v * (DIM / 2);
  float2 tv = *(const float2*)(tmp + (size_t)v * DIM + 2 * c2);
  float2 sc = scs[c2], sh = shs[c2];
  float2* hp = (float2*)(h + (size_t)v * DIM + 2 * c2);
  float2 hv = *hp;
  float x0 = fmaf(tv.x, sc.x, sh.x); x0 = fmaxf(x0, 0.f);
  float x1 = fmaf(tv.y, sc.y, sh.y); x1 = fmaxf(x1, 0.f);
  hv.x += x0; hv.y += x1;
  *hp = hv;
}

// ---------------- layer-3 fused: BN+ReLU+residual -> per-graph sum ----------------
__global__ __launch_bounds__(192) void gsum_kernel(
    const float* __restrict__ tmp, const float* __restrict__ stats,
    const float* __restrict__ gamma, const float* __restrict__ beta,
    const float* __restrict__ h, const int* __restrict__ gids,
    float* __restrict__ hgp) {
  int t = threadIdx.x;
  if (t > DIM) return;  // t==DIM is the count thread; no barriers below
  float sc = 0.f, sh = 0.f;
  if (t < DIM) {
    float mu = stats[t] * (1.f / N_NODES);
    float var = stats[DIM + t] * (1.f / N_NODES) - mu * mu;
    sc = gamma[t] * rsqrtf(var + BN_EPS);
    sh = beta[t] - mu * sc;
  }
  int r0 = blockIdx.x * 64;
  int part = blockIdx.x & (GS_PART - 1);
  float accv = 0.f;
  int g_prev = gids[r0];
  for (int rr = 0; rr < 64; rr++) {
    int r = r0 + rr;
    if (r >= N_NODES) break;
    int g = gids[r];
    if (g != g_prev) {
      atomicAdd(&hgp[(size_t)(part * N_GRAPHS + g_prev) * GS_STRIDE + t], accv);
      accv = 0.f; g_prev = g;
    }
    float val;
    if (t < DIM) {
      float x = fmaf(tmp[(size_t)r * DIM + t], sc, sh);
      x = fmaxf(x, 0.f);
      val = h[(size_t)r * DIM + t] + x;
    } else {
      val = 1.f;
    }
    accv += val;
  }
  atomicAdd(&hgp[(size_t)(part * N_GRAPHS + g_prev) * GS_STRIDE + t], accv);
}

// ---------------- fused mean + MLP readout: one block per graph ----------------
__global__ __launch_bounds__(256) void mlp_kernel(
    const float* __restrict__ hgp,
    const float* __restrict__ W1, const float* __restrict__ b1,
    const float* __restrict__ W2, const float* __restrict__ b2,
    const float* __restrict__ W3, const float* __restrict__ b3,
    float* __restrict__ out) {
  __shared__ float hrow[DIM];
  __shared__ float x1[73];
  __shared__ float x2[36];
  int g = blockIdx.x;
  int t = threadIdx.x;
  if (t < DIM) {
    float s = 0.f, cnt = 0.f;
#pragma unroll
    for (int p = 0; p < GS_PART; p++) {
      const float* row = hgp + (size_t)(p * N_GRAPHS + g) * GS_STRIDE;
      s += row[t];
      cnt += row[DIM];
    }
    hrow[t] = s / cnt;
  }
  __syncthreads();
  if (t < 73) {
    float s = b1[t];
    for (int k = 0; k < DIM; k++) s = fmaf(hrow[k], W1[k * 73 + t], s);
    x1[t] = s > 0.f ? s : 0.f;
  }
  __syncthreads();
  if (t < 36) {
    float s = b2[t];
    for (int k = 0; k < 73; k++) s = fmaf(x1[k], W2[k * 36 + t], s);
    x2[t] = s > 0.f ? s : 0.f;
  }
  __syncthreads();
  if (t < 10) {
    float s = b3[t];
    for (int k = 0; k < 36; k++) s = fmaf(x2[k], W3[k * 10 + t], s);
    out[g * 10 + t] = s;
  }
}

extern "C" void kernel_launch(void* const* d_in, const int* in_sizes, int n_in,
                              void* d_out, int out_size, void* d_ws, size_t ws_size,
                              hipStream_t stream) {
  const float* nodes_feat = (const float*)d_in[0];
  const float* snorm  = (const float*)d_in[1];
  const float* W_emb  = (const float*)d_in[2];
  const float* b_emb  = (const float*)d_in[3];
  const float* Ws     = (const float*)d_in[4];
  const float* bs     = (const float*)d_in[5];
  const float* gammas = (const float*)d_in[6];
  const float* betas  = (const float*)d_in[7];
  const float* W1 = (const float*)d_in[8];
  const float* b1 = (const float*)d_in[9];
  const float* W2 = (const float*)d_in[10];
  const float* b2 = (const float*)d_in[11];
  const float* W3 = (const float*)d_in[12];
  const float* b3 = (const float*)d_in[13];
  const int* src  = (const int*)d_in[14];
  const int* dst  = (const int*)d_in[15];
  const int* gids = (const int*)d_in[16];
  float* out = (float*)d_out;

  char* base = (char*)d_ws;
  size_t off = 0;
  auto alloc = [&](size_t bytes) { void* p = base + off; off += (bytes + 255) & ~size_t(255); return p; };
  float* h   = (float*)alloc((size_t)N_NODES * DIM * 4);
  float* tmp = (float*)alloc((size_t)N_NODES * DIM * 4);
  char* zstart = base + off;
  int* deg_out = (int*)alloc(N_NODES * 4);
  int* deg_in  = (int*)alloc(N_NODES * 4);
  int* fill    = (int*)alloc(N_NODES * 4);
  float* stats = (float*)alloc(4 * 2 * DIM * 4);   // per layer: [sum, sumsq]
  float* hgp   = (float*)alloc((size_t)GS_PART * N_GRAPHS * GS_STRIDE * 4);
  size_t zbytes = (size_t)((base + off) - zstart);
  int* row_ptr = (int*)alloc((N_NODES + 1) * 4);
  float* norm_out = (float*)alloc(N_NODES * 4);
  float* norm_in  = (float*)alloc(N_NODES * 4);
  int* csr   = (int*)alloc((size_t)N_EDGES * 4);
  int* bsums = (int*)alloc(128 * 4);
  int* bofs  = (int*)alloc(128 * 4);
  float* Wt  = (float*)alloc((size_t)5 * DIM * WT_STRIDE * 4);

  hipMemsetAsync(zstart, 0, zbytes, stream);

  hist_kernel<<<(N_EDGES + 255) / 256, 256, 0, stream>>>(src, dst, deg_out, deg_in);
  norm_kernel<<<(N_NODES + 255) / 256, 256, 0, stream>>>(deg_out, deg_in, norm_out, norm_in);
  int nb = (N_NODES + 1023) / 1024;
  scan1_kernel<<<nb, 256, 0, stream>>>(deg_in, bsums);
  scan2_kernel<<<1, 64, 0, stream>>>(bsums, bofs, row_ptr, nb);
  scan3_kernel<<<nb, 256, 0, stream>>>(deg_in, bofs, row_ptr);
  csr_fill_kernel<<<(N_EDGES + 255) / 256, 256, 0, stream>>>(src, dst, row_ptr, fill, csr);
  dim3 wtg((DIM * WT_STRIDE + 255) / 256, 5);
  wtrans_kernel<<<wtg, 256, 0, stream>>>(W_emb, Ws, Wt);

  gemm_kernel<false><<<(N_NODES + 63) / 64, 256, 0, stream>>>(nodes_feat, Wt, b_emb, nullptr, h, nullptr);

  for (int l = 0; l < 4; l++) {
    float* st = stats + l * 2 * DIM;
    agg_kernel<<<(N_NODES + 3) / 4, 256, 0, stream>>>(h, row_ptr, csr, norm_out, norm_in, tmp);
    gemm_kernel<true><<<(N_NODES + 63) / 64, 256, 0, stream>>>(
        tmp, Wt + (size_t)(l + 1) * DIM * WT_STRIDE, bs + l * DIM, snorm, tmp, st);
    if (l < 3) {
      bn_kernel<<<(N_NODES * (DIM / 2) + 255) / 256, 256, 0, stream>>>(
          tmp, st, gammas + l * DIM, betas + l * DIM, h);
    } else {
      gsum_kernel<<<(N_NODES + 63) / 64, 192, 0, stream>>>(
          tmp, st, gammas + l * DIM, betas + l * DIM, h, gids, hgp);
    }
  }

  mlp_kernel<<<N_GRAPHS, 256, 0, stream>>>(hgp, W1, b1, W2, b2, W3, b3, out);
}

// Round 4
// 1022.800 us; speedup vs baseline: 1.5963x; 1.3488x over previous
//
#include <hip/hip_runtime.h>

#define N_NODES 100000
#define N_EDGES 500000
#define N_GRAPHS 100
#define DIM 146
#define APAD 160        // padded bf16 A row stride (16B-aligned, 5 k-chunks of 32)
#define BN_EPS 1e-5f
#define GS_PART 8
#define GS_STRIDE 147   // 146 cols + 1 count slot

typedef __bf16 bf16x8 __attribute__((ext_vector_type(8)));
typedef float floatx4 __attribute__((ext_vector_type(4)));
typedef unsigned short ushort_t;
typedef unsigned int uint_t;

__device__ inline ushort_t f2bf(float x) {
  uint_t u = __float_as_uint(x);
  uint_t r = (u + 0x7fffu + ((u >> 16) & 1u)) >> 16;   // RNE
  return (ushort_t)r;
}
__device__ inline float bf2f(ushort_t b) { return __uint_as_float((uint_t)b << 16); }

// ---------------- prep kernels ----------------
__global__ void hist_kernel(const int* __restrict__ src, const int* __restrict__ dst,
                            int* __restrict__ deg_out, int* __restrict__ deg_in) {
  int e = blockIdx.x * 256 + threadIdx.x;
  if (e < N_EDGES) {
    atomicAdd(&deg_out[src[e]], 1);
    atomicAdd(&deg_in[dst[e]], 1);
  }
}

__global__ void norm_kernel(const int* __restrict__ deg_out, const int* __restrict__ deg_in,
                            float* __restrict__ norm_out, float* __restrict__ norm_in) {
  int v = blockIdx.x * 256 + threadIdx.x;
  if (v < N_NODES) {
    norm_out[v] = rsqrtf((float)max(deg_out[v], 1));
    norm_in[v]  = rsqrtf((float)max(deg_in[v], 1));
  }
}

__global__ void scan1_kernel(const int* __restrict__ deg_in, int* __restrict__ bsums) {
  __shared__ int sred[256];
  int t0 = blockIdx.x * 1024 + threadIdx.x * 4;
  int s = 0;
#pragma unroll
  for (int i = 0; i < 4; i++) { int v = t0 + i; s += (v < N_NODES) ? deg_in[v] : 0; }
  sred[threadIdx.x] = s; __syncthreads();
  for (int off = 128; off > 0; off >>= 1) {
    if (threadIdx.x < off) sred[threadIdx.x] += sred[threadIdx.x + off];
    __syncthreads();
  }
  if (threadIdx.x == 0) bsums[blockIdx.x] = sred[0];
}

__global__ void scan2_kernel(const int* __restrict__ bsums, int* __restrict__ bofs,
                             int* __restrict__ row_ptr, int nb) {
  if (threadIdx.x == 0 && blockIdx.x == 0) {
    int run = 0;
    for (int i = 0; i < nb; i++) { bofs[i] = run; run += bsums[i]; }
    row_ptr[N_NODES] = run;
  }
}

__global__ void scan3_kernel(const int* __restrict__ deg_in, const int* __restrict__ bofs,
                             int* __restrict__ row_ptr) {
  __shared__ int ssc[256];
  int t0 = blockIdx.x * 1024 + threadIdx.x * 4;
  int v4[4]; int s = 0;
#pragma unroll
  for (int i = 0; i < 4; i++) { int v = t0 + i; v4[i] = (v < N_NODES) ? deg_in[v] : 0; s += v4[i]; }
  ssc[threadIdx.x] = s; __syncthreads();
  for (int off = 1; off < 256; off <<= 1) {
    int t = (threadIdx.x >= off) ? ssc[threadIdx.x - off] : 0;
    __syncthreads();
    ssc[threadIdx.x] += t;
    __syncthreads();
  }
  int ex = ssc[threadIdx.x] - s + bofs[blockIdx.x];
#pragma unroll
  for (int i = 0; i < 4; i++) {
    int v = t0 + i;
    if (v < N_NODES) { row_ptr[v] = ex; ex += v4[i]; }
  }
}

__global__ void csr_fill_kernel(const int* __restrict__ src, const int* __restrict__ dst,
                                const int* __restrict__ row_ptr, int* __restrict__ fill,
                                int* __restrict__ csr) {
  int e = blockIdx.x * 256 + threadIdx.x;
  if (e < N_EDGES) {
    int d = dst[e];
    int slot = atomicAdd(&fill[d], 1);
    csr[row_ptr[d] + slot] = src[e];
  }
}

// ---------- W swizzle into MFMA B-fragment order, split hi/lo bf16 ----------
// Wb elem = ((((m*5+kc)*10+nt)*2+hl)*64+lane)*8+j ; k=kc*32+(lane>>4)*8+j ; n=nt*16+(lane&15)
__global__ void wtrans_kernel(const float* __restrict__ W_emb, const float* __restrict__ Ws,
                              ushort_t* __restrict__ Wb) {
  int idx = blockIdx.x * 256 + threadIdx.x;
  if (idx >= 5 * 5 * 10 * 64 * 8) return;
  int j = idx & 7;
  int t = idx >> 3;
  int lane = t & 63; t >>= 6;
  int nt = t % 10; t /= 10;
  int kc = t % 5;
  int m = t / 5;
  const float* W = (m == 0) ? W_emb : Ws + (size_t)(m - 1) * DIM * DIM;
  int k = kc * 32 + (lane >> 4) * 8 + j;
  int n = nt * 16 + (lane & 15);
  float w = (k < DIM && n < DIM) ? W[k * DIM + n] : 0.f;
  ushort_t hi = f2bf(w);
  float lo = w - bf2f(hi);
  size_t base = (size_t)((((m * 5 + kc) * 10 + nt) * 2) * 64 + lane) * 8 + j;
  Wb[base] = hi;
  Wb[base + 512] = f2bf(lo);
}

// ---------- nodes_feat fp32 -> padded bf16 ----------
__global__ void nf2bf_kernel(const float* __restrict__ nf, ushort_t* __restrict__ xb) {
  int idx = blockIdx.x * 256 + threadIdx.x;
  if (idx >= N_NODES * (APAD / 2)) return;
  int v = idx / (APAD / 2), u = idx - v * (APAD / 2);
  int c = 2 * u;
  float x0 = (c < DIM) ? nf[(size_t)v * DIM + c] : 0.f;
  float x1 = (c + 1 < DIM) ? nf[(size_t)v * DIM + c + 1] : 0.f;
  ((uint_t*)xb)[idx] = (uint_t)f2bf(x0) | ((uint_t)f2bf(x1) << 16);
}

// ---------------- MFMA GEMM: out = A(bf16) @ W(split bf16) + b ----------------
// Per wave: 32 rows (2 A-frags) x 160 cols (10 n-tiles), K=160 in 5 chunks of 32.
// 100 MFMAs/wave. C/D layout: col=lane&15, row=quad*4+reg.
template <bool LAYER>
__global__ __launch_bounds__(256, 4) void gemm_kernel(
    const ushort_t* __restrict__ Abf, const ushort_t* __restrict__ Wb,
    const float* __restrict__ bias, const float* __restrict__ snorm,
    float* __restrict__ out, float* __restrict__ stats) {
  __shared__ float sred[2 * DIM];
  if (LAYER) {
    for (int i = threadIdx.x; i < 2 * DIM; i += 256) sred[i] = 0.f;
    __syncthreads();
  }
  int wave = threadIdx.x >> 6, lane = threadIdx.x & 63;
  int quad = lane >> 4, l16 = lane & 15;
  int m0 = blockIdx.x * 128 + wave * 32;
  int ra = min(m0 + l16, N_NODES - 1);
  int rb = min(m0 + 16 + l16, N_NODES - 1);
  const ushort_t* ap0 = Abf + (size_t)ra * APAD + quad * 8;
  const ushort_t* ap1 = Abf + (size_t)rb * APAD + quad * 8;

  floatx4 acc[2][10];
#pragma unroll
  for (int s = 0; s < 2; s++)
#pragma unroll
    for (int nt = 0; nt < 10; nt++) acc[s][nt] = (floatx4){0.f, 0.f, 0.f, 0.f};

  for (int kc = 0; kc < 5; kc++) {
    bf16x8 a0 = *(const bf16x8*)(ap0 + kc * 32);
    bf16x8 a1 = *(const bf16x8*)(ap1 + kc * 32);
    const ushort_t* wp = Wb + (size_t)(kc * 10) * 1024 + lane * 8;
#pragma unroll
    for (int nt = 0; nt < 10; nt++) {
      bf16x8 bh = *(const bf16x8*)(wp);
      bf16x8 bl = *(const bf16x8*)(wp + 512);
      acc[0][nt] = __builtin_amdgcn_mfma_f32_16x16x32_bf16(a0, bh, acc[0][nt], 0, 0, 0);
      acc[1][nt] = __builtin_amdgcn_mfma_f32_16x16x32_bf16(a1, bh, acc[1][nt], 0, 0, 0);
      acc[0][nt] = __builtin_amdgcn_mfma_f32_16x16x32_bf16(a0, bl, acc[0][nt], 0, 0, 0);
      acc[1][nt] = __builtin_amdgcn_mfma_f32_16x16x32_bf16(a1, bl, acc[1][nt], 0, 0, 0);
      wp += 1024;
    }
  }

  // epilogue: rows m0 + s*16 + quad*4 + r
  float sn[2][4];
  if (LAYER) {
#pragma unroll
    for (int s = 0; s < 2; s++)
#pragma unroll
      for (int r = 0; r < 4; r++) sn[s][r] = snorm[min(m0 + s * 16 + quad * 4 + r, N_NODES - 1)];
  }
#pragma unroll
  for (int nt = 0; nt < 10; nt++) {
    int c = nt * 16 + l16;
    if (c < DIM) {
      float b = bias[c];
      float ssum = 0.f, ssq = 0.f;
#pragma unroll
      for (int s = 0; s < 2; s++) {
#pragma unroll
        for (int r = 0; r < 4; r++) {
          int row = m0 + s * 16 + quad * 4 + r;
          if (row < N_NODES) {
            float val = acc[s][nt][r] + b;
            if (LAYER) val *= sn[s][r];
            out[(size_t)row * DIM + c] = val;
            if (LAYER) { ssum += val; ssq += val * val; }
          }
        }
      }
      if (LAYER) {
        // reduce across the 4 quads (same c), then one LDS atomic per column
        ssum += __shfl_xor(ssum, 16, 64); ssum += __shfl_xor(ssum, 32, 64);
        ssq  += __shfl_xor(ssq, 16, 64);  ssq  += __shfl_xor(ssq, 32, 64);
        if (quad == 0) {
          atomicAdd(&sred[c], ssum);
          atomicAdd(&sred[DIM + c], ssq);
        }
      }
    }
  }
  if (LAYER) {
    __syncthreads();
    for (int i = threadIdx.x; i < 2 * DIM; i += 256) atomicAdd(&stats[i], sred[i]);
  }
}

// ------- aggregation: one wave per destination node, writes bf16 (stride APAD) -------
__global__ __launch_bounds__(256) void agg_kernel(
    const float* __restrict__ h, const int* __restrict__ row_ptr, const int* __restrict__ csr,
    const float* __restrict__ norm_out, const float* __restrict__ norm_in,
    ushort_t* __restrict__ xb) {
  int wid = threadIdx.x >> 6, lane = threadIdx.x & 63;
  int v = blockIdx.x * 4 + wid;
  if (v >= N_NODES) return;
  int e0 = row_ptr[v], e1 = row_ptr[v + 1];
  bool ext = lane < 9;
  float a0 = 0.f, a1 = 0.f, a2 = 0.f, a3 = 0.f;
  for (int e = e0; e < e1; e++) {
    int s = csr[e];
    float sc = norm_out[s];
    const float* hr = h + (size_t)s * DIM;
    float2 x = *(const float2*)(hr + 2 * lane);
    a0 = fmaf(x.x, sc, a0);
    a1 = fmaf(x.y, sc, a1);
    if (ext) {
      float2 y = *(const float2*)(hr + 128 + 2 * lane);
      a2 = fmaf(y.x, sc, a2);
      a3 = fmaf(y.y, sc, a3);
    }
  }
  float ni = norm_in[v];
  uint_t* ow = (uint_t*)(xb + (size_t)v * APAD);
  ow[lane] = (uint_t)f2bf(a0 * ni) | ((uint_t)f2bf(a1 * ni) << 16);
  if (ext) ow[64 + lane] = (uint_t)f2bf(a2 * ni) | ((uint_t)f2bf(a3 * ni) << 16);
}

// ---------------- fused BN-prep + BN + ReLU + residual (in-place on h) ----------------
__global__ __launch_bounds__(256) void bn_kernel(const float* __restrict__ tmp,
                                                 const float* __restrict__ stats,
                                                 const float* __restrict__ gamma,
                                                 const float* __restrict__ beta,
                                                 float* __restrict__ h) {
  __shared__ float2 scs[DIM / 2], shs[DIM / 2];
  int t = threadIdx.x;
  if (t < DIM / 2) {
    int c0 = 2 * t, c1 = c0 + 1;
    float mu0 = stats[c0] * (1.f / N_NODES), mu1 = stats[c1] * (1.f / N_NODES);
    float v0 = stats[DIM + c0] * (1.f / N_NODES) - mu0 * mu0;
    float v1 = stats[DIM + c1] * (1.f / N_NODES) - mu1 * mu1;
    float s0 = gamma[c0] * rsqrtf(v0 + BN_EPS), s1 = gamma[c1] * rsqrtf(v1 + BN_EPS);
    scs[t] = make_float2(s0, s1);
    shs[t] = make_float2(beta[c0] - mu0 * s0, beta[c1] - mu1 * s1);
  }
  __syncthreads();
  int idx = blockIdx.x * 256 + t;
  if (idx >= N_NODES * (DIM / 2)) return;
  int v = idx / (DIM / 2), c2 = idx - v * (DIM / 2);
  float2 tv = *(const float2*)(tmp + (size_t)v * DIM + 2 * c2);
  float2 sc = scs[c2], sh = shs[c2];
  float2* hp = (float2*)(h + (size_t)v * DIM + 2 * c2);
  float2 hv = *hp;
  float x0 = fmaf(tv.x, sc.x, sh.x); x0 = fmaxf(x0, 0.f);
  float x1 = fmaf(tv.y, sc.y, sh.y); x1 = fmaxf(x1, 0.f);
  hv.x += x0; hv.y += x1;
  *hp = hv;
}

// ---------------- layer-3 fused: BN+ReLU+residual -> per-graph sum ----------------
__global__ __launch_bounds__(192) void gsum_kernel(
    const float* __restrict__ tmp, const float* __restrict__ stats,
    const float* __restrict__ gamma, const float* __restrict__ beta,
    const float* __restrict__ h, const int* __restrict__ gids,
    float* __restrict__ hgp) {
  int t = threadIdx.x;
  if (t > DIM) return;  // t==DIM is the count thread; no barriers below
  float sc = 0.f, sh = 0.f;
  if (t < DIM) {
    float mu = stats[t] * (1.f / N_NODES);
    float var = stats[DIM + t] * (1.f / N_NODES) - mu * mu;
    sc = gamma[t] * rsqrtf(var + BN_EPS);
    sh = beta[t] - mu * sc;
  }
  int r0 = blockIdx.x * 64;
  int part = blockIdx.x & (GS_PART - 1);
  float accv = 0.f;
  int g_prev = gids[r0];
  for (int rr = 0; rr < 64; rr++) {
    int r = r0 + rr;
    if (r >= N_NODES) break;
    int g = gids[r];
    if (g != g_prev) {
      atomicAdd(&hgp[(size_t)(part * N_GRAPHS + g_prev) * GS_STRIDE + t], accv);
      accv = 0.f; g_prev = g;
    }
    float val;
    if (t < DIM) {
      float x = fmaf(tmp[(size_t)r * DIM + t], sc, sh);
      x = fmaxf(x, 0.f);
      val = h[(size_t)r * DIM + t] + x;
    } else {
      val = 1.f;
    }
    accv += val;
  }
  atomicAdd(&hgp[(size_t)(part * N_GRAPHS + g_prev) * GS_STRIDE + t], accv);
}

// ---------------- fused mean + MLP readout: one block per graph ----------------
__global__ __launch_bounds__(256) void mlp_kernel(
    const float* __restrict__ hgp,
    const float* __restrict__ W1, const float* __restrict__ b1,
    const float* __restrict__ W2, const float* __restrict__ b2,
    const float* __restrict__ W3, const float* __restrict__ b3,
    float* __restrict__ out) {
  __shared__ float hrow[DIM];
  __shared__ float x1[73];
  __shared__ float x2[36];
  int g = blockIdx.x;
  int t = threadIdx.x;
  if (t < DIM) {
    float s = 0.f, cnt = 0.f;
#pragma unroll
    for (int p = 0; p < GS_PART; p++) {
      const float* row = hgp + (size_t)(p * N_GRAPHS + g) * GS_STRIDE;
      s += row[t];
      cnt += row[DIM];
    }
    hrow[t] = s / cnt;
  }
  __syncthreads();
  if (t < 73) {
    float s = b1[t];
    for (int k = 0; k < DIM; k++) s = fmaf(hrow[k], W1[k * 73 + t], s);
    x1[t] = s > 0.f ? s : 0.f;
  }
  __syncthreads();
  if (t < 36) {
    float s = b2[t];
    for (int k = 0; k < 73; k++) s = fmaf(x1[k], W2[k * 36 + t], s);
    x2[t] = s > 0.f ? s : 0.f;
  }
  __syncthreads();
  if (t < 10) {
    float s = b3[t];
    for (int k = 0; k < 36; k++) s = fmaf(x2[k], W3[k * 10 + t], s);
    out[g * 10 + t] = s;
  }
}

extern "C" void kernel_launch(void* const* d_in, const int* in_sizes, int n_in,
                              void* d_out, int out_size, void* d_ws, size_t ws_size,
                              hipStream_t stream) {
  const float* nodes_feat = (const float*)d_in[0];
  const float* snorm  = (const float*)d_in[1];
  const float* W_emb  = (const float*)d_in[2];
  const float* b_emb  = (const float*)d_in[3];
  const float* Ws     = (const float*)d_in[4];
  const float* bs     = (const float*)d_in[5];
  const float* gammas = (const float*)d_in[6];
  const float* betas  = (const float*)d_in[7];
  const float* W1 = (const float*)d_in[8];
  const float* b1 = (const float*)d_in[9];
  const float* W2 = (const float*)d_in[10];
  const float* b2 = (const float*)d_in[11];
  const float* W3 = (const float*)d_in[12];
  const float* b3 = (const float*)d_in[13];
  const int* src  = (const int*)d_in[14];
  const int* dst  = (const int*)d_in[15];
  const int* gids = (const int*)d_in[16];
  float* out = (float*)d_out;

  char* base = (char*)d_ws;
  size_t off = 0;
  auto alloc = [&](size_t bytes) { void* p = base + off; off += (bytes + 255) & ~size_t(255); return p; };
  float* h    = (float*)alloc((size_t)N_NODES * DIM * 4);
  float* tmp  = (float*)alloc((size_t)N_NODES * DIM * 4);
  ushort_t* xb = (ushort_t*)alloc((size_t)N_NODES * APAD * 2);  // bf16 A (feat, then agg out)
  char* zstart = base + off;
  int* deg_out = (int*)alloc(N_NODES * 4);
  int* deg_in  = (int*)alloc(N_NODES * 4);
  int* fill    = (int*)alloc(N_NODES * 4);
  float* stats = (float*)alloc(4 * 2 * DIM * 4);   // per layer: [sum, sumsq]
  float* hgp   = (float*)alloc((size_t)GS_PART * N_GRAPHS * GS_STRIDE * 4);
  size_t zbytes = (size_t)((base + off) - zstart);
  int* row_ptr = (int*)alloc((N_NODES + 1) * 4);
  float* norm_out = (float*)alloc(N_NODES * 4);
  float* norm_in  = (float*)alloc(N_NODES * 4);
  int* csr   = (int*)alloc((size_t)N_EDGES * 4);
  int* bsums = (int*)alloc(128 * 4);
  int* bofs  = (int*)alloc(128 * 4);
  ushort_t* Wb = (ushort_t*)alloc((size_t)5 * 5 * 10 * 2 * 64 * 8 * 2);  // 5 matrices, hi/lo frags

  hipMemsetAsync(zstart, 0, zbytes, stream);

  hist_kernel<<<(N_EDGES + 255) / 256, 256, 0, stream>>>(src, dst, deg_out, deg_in);
  norm_kernel<<<(N_NODES + 255) / 256, 256, 0, stream>>>(deg_out, deg_in, norm_out, norm_in);
  int nb = (N_NODES + 1023) / 1024;
  scan1_kernel<<<nb, 256, 0, stream>>>(deg_in, bsums);
  scan2_kernel<<<1, 64, 0, stream>>>(bsums, bofs, row_ptr, nb);
  scan3_kernel<<<nb, 256, 0, stream>>>(deg_in, bofs, row_ptr);
  csr_fill_kernel<<<(N_EDGES + 255) / 256, 256, 0, stream>>>(src, dst, row_ptr, fill, csr);
  wtrans_kernel<<<(5 * 5 * 10 * 64 * 8 + 255) / 256, 256, 0, stream>>>(W_emb, Ws, Wb);
  nf2bf_kernel<<<(N_NODES * (APAD / 2) + 255) / 256, 256, 0, stream>>>(nodes_feat, xb);

  const int GB = (N_NODES + 127) / 128;
  const size_t WM = (size_t)5 * 10 * 2 * 64 * 8;  // elems per matrix

  gemm_kernel<false><<<GB, 256, 0, stream>>>(xb, Wb, b_emb, nullptr, h, nullptr);

  for (int l = 0; l < 4; l++) {
    float* st = stats + l * 2 * DIM;
    agg_kernel<<<(N_NODES + 3) / 4, 256, 0, stream>>>(h, row_ptr, csr, norm_out, norm_in, xb);
    gemm_kernel<true><<<GB, 256, 0, stream>>>(xb, Wb + (size_t)(l + 1) * WM,
                                              bs + l * DIM, snorm, tmp, st);
    if (l < 3) {
      bn_kernel<<<(N_NODES * (DIM / 2) + 255) / 256, 256, 0, stream>>>(
          tmp, st, gammas + l * DIM, betas + l * DIM, h);
    } else {
      gsum_kernel<<<(N_NODES + 63) / 64, 192, 0, stream>>>(
          tmp, st, gammas + l * DIM, betas + l * DIM, h, gids, hgp);
    }
  }

  mlp_kernel<<<N_GRAPHS, 256, 0, stream>>>(hgp, W1, b1, W2, b2, W3, b3, out);
}

// Round 5
// 894.108 us; speedup vs baseline: 1.8261x; 1.1439x over previous
//
#include <hip/hip_runtime.h>

#define N_NODES 100000
#define N_EDGES 500000
#define N_GRAPHS 100
#define DIM 146
#define APAD 160        // padded bf16 row stride (16B-aligned, 5 k-chunks of 32)
#define BN_EPS 1e-5f
#define GS_PART 8
#define GS_STRIDE 147   // 146 cols + 1 count slot

typedef __bf16 bf16x8 __attribute__((ext_vector_type(8)));
typedef float floatx4 __attribute__((ext_vector_type(4)));
typedef unsigned short ushort_t;
typedef unsigned int uint_t;

__device__ inline ushort_t f2bf(float x) {
  uint_t u = __float_as_uint(x);
  uint_t r = (u + 0x7fffu + ((u >> 16) & 1u)) >> 16;   // RNE
  return (ushort_t)r;
}
__device__ inline float bf2f(ushort_t b) { return __uint_as_float((uint_t)b << 16); }
__device__ inline uint_t pack2bf(float a, float b) {
  return (uint_t)f2bf(a) | ((uint_t)f2bf(b) << 16);
}
__device__ inline float bflo(uint_t u) { return __uint_as_float(u << 16); }
__device__ inline float bfhi(uint_t u) { return __uint_as_float(u & 0xffff0000u); }

// ---------------- prep kernels ----------------
__global__ void hist_kernel(const int* __restrict__ src, const int* __restrict__ dst,
                            int* __restrict__ deg_out, int* __restrict__ deg_in) {
  int e = blockIdx.x * 256 + threadIdx.x;
  if (e < N_EDGES) {
    atomicAdd(&deg_out[src[e]], 1);
    atomicAdd(&deg_in[dst[e]], 1);
  }
}

__global__ void norm_kernel(const int* __restrict__ deg_out, const int* __restrict__ deg_in,
                            float* __restrict__ norm_out, float* __restrict__ norm_in) {
  int v = blockIdx.x * 256 + threadIdx.x;
  if (v < N_NODES) {
    norm_out[v] = rsqrtf((float)max(deg_out[v], 1));
    norm_in[v]  = rsqrtf((float)max(deg_in[v], 1));
  }
}

__global__ void scan1_kernel(const int* __restrict__ deg_in, int* __restrict__ bsums) {
  __shared__ int sred[256];
  int t0 = blockIdx.x * 1024 + threadIdx.x * 4;
  int s = 0;
#pragma unroll
  for (int i = 0; i < 4; i++) { int v = t0 + i; s += (v < N_NODES) ? deg_in[v] : 0; }
  sred[threadIdx.x] = s; __syncthreads();
  for (int off = 128; off > 0; off >>= 1) {
    if (threadIdx.x < off) sred[threadIdx.x] += sred[threadIdx.x + off];
    __syncthreads();
  }
  if (threadIdx.x == 0) bsums[blockIdx.x] = sred[0];
}

__global__ void scan2_kernel(const int* __restrict__ bsums, int* __restrict__ bofs,
                             int* __restrict__ row_ptr, int nb) {
  if (threadIdx.x == 0 && blockIdx.x == 0) {
    int run = 0;
    for (int i = 0; i < nb; i++) { bofs[i] = run; run += bsums[i]; }
    row_ptr[N_NODES] = run;
  }
}

__global__ void scan3_kernel(const int* __restrict__ deg_in, const int* __restrict__ bofs,
                             int* __restrict__ row_ptr) {
  __shared__ int ssc[256];
  int t0 = blockIdx.x * 1024 + threadIdx.x * 4;
  int v4[4]; int s = 0;
#pragma unroll
  for (int i = 0; i < 4; i++) { int v = t0 + i; v4[i] = (v < N_NODES) ? deg_in[v] : 0; s += v4[i]; }
  ssc[threadIdx.x] = s; __syncthreads();
  for (int off = 1; off < 256; off <<= 1) {
    int t = (threadIdx.x >= off) ? ssc[threadIdx.x - off] : 0;
    __syncthreads();
    ssc[threadIdx.x] += t;
    __syncthreads();
  }
  int ex = ssc[threadIdx.x] - s + bofs[blockIdx.x];
#pragma unroll
  for (int i = 0; i < 4; i++) {
    int v = t0 + i;
    if (v < N_NODES) { row_ptr[v] = ex; ex += v4[i]; }
  }
}

__global__ void csr_fill_kernel(const int* __restrict__ src, const int* __restrict__ dst,
                                const int* __restrict__ row_ptr, int* __restrict__ fill,
                                int* __restrict__ csr) {
  int e = blockIdx.x * 256 + threadIdx.x;
  if (e < N_EDGES) {
    int d = dst[e];
    int slot = atomicAdd(&fill[d], 1);
    csr[row_ptr[d] + slot] = src[e];
  }
}

// ---------- W swizzle into MFMA B-fragment order, split hi/lo bf16 ----------
__global__ void wtrans_kernel(const float* __restrict__ W_emb, const float* __restrict__ Ws,
                              ushort_t* __restrict__ Wb) {
  int idx = blockIdx.x * 256 + threadIdx.x;
  if (idx >= 5 * 5 * 10 * 64 * 8) return;
  int j = idx & 7;
  int t = idx >> 3;
  int lane = t & 63; t >>= 6;
  int nt = t % 10; t /= 10;
  int kc = t % 5;
  int m = t / 5;
  const float* W = (m == 0) ? W_emb : Ws + (size_t)(m - 1) * DIM * DIM;
  int k = kc * 32 + (lane >> 4) * 8 + j;
  int n = nt * 16 + (lane & 15);
  float w = (k < DIM && n < DIM) ? W[k * DIM + n] : 0.f;
  ushort_t hi = f2bf(w);
  float lo = w - bf2f(hi);
  size_t base = (size_t)((((m * 5 + kc) * 10 + nt) * 2) * 64 + lane) * 8 + j;
  Wb[base] = hi;
  Wb[base + 512] = f2bf(lo);
}

// ---------- nodes_feat fp32 -> padded bf16 ----------
__global__ void nf2bf_kernel(const float* __restrict__ nf, ushort_t* __restrict__ xb) {
  int idx = blockIdx.x * 256 + threadIdx.x;
  if (idx >= N_NODES * (APAD / 2)) return;
  int v = idx / (APAD / 2), u = idx - v * (APAD / 2);
  int c = 2 * u;
  float x0 = (c < DIM) ? nf[(size_t)v * DIM + c] : 0.f;
  float x1 = (c + 1 < DIM) ? nf[(size_t)v * DIM + c + 1] : 0.f;
  ((uint_t*)xb)[idx] = pack2bf(x0, x1);
}

// ---------- h fp32 -> hb bf16 pre-scaled by norm_out (after embedding GEMM) ----------
__global__ void h2hb_kernel(const float* __restrict__ h, const float* __restrict__ norm_out,
                            ushort_t* __restrict__ hb) {
  int idx = blockIdx.x * 256 + threadIdx.x;
  if (idx >= N_NODES * (APAD / 2)) return;
  int v = idx / (APAD / 2), u = idx - v * (APAD / 2);
  int c = 2 * u;
  float no = norm_out[v];
  float x0 = (c < DIM) ? h[(size_t)v * DIM + c] * no : 0.f;
  float x1 = (c + 1 < DIM) ? h[(size_t)v * DIM + c + 1] * no : 0.f;
  ((uint_t*)hb)[idx] = pack2bf(x0, x1);
}

// ---------------- MFMA GEMM: out = A(bf16) @ W(split bf16) + b ----------------
template <bool LAYER>
__global__ __launch_bounds__(256, 4) void gemm_kernel(
    const ushort_t* __restrict__ Abf, const ushort_t* __restrict__ Wb,
    const float* __restrict__ bias, const float* __restrict__ snorm,
    float* __restrict__ out, float* __restrict__ stats) {
  __shared__ float sred[2 * DIM];
  if (LAYER) {
    for (int i = threadIdx.x; i < 2 * DIM; i += 256) sred[i] = 0.f;
    __syncthreads();
  }
  int wave = threadIdx.x >> 6, lane = threadIdx.x & 63;
  int quad = lane >> 4, l16 = lane & 15;
  int m0 = blockIdx.x * 128 + wave * 32;
  int ra = min(m0 + l16, N_NODES - 1);
  int rb = min(m0 + 16 + l16, N_NODES - 1);
  const ushort_t* ap0 = Abf + (size_t)ra * APAD + quad * 8;
  const ushort_t* ap1 = Abf + (size_t)rb * APAD + quad * 8;

  floatx4 acc[2][10];
#pragma unroll
  for (int s = 0; s < 2; s++)
#pragma unroll
    for (int nt = 0; nt < 10; nt++) acc[s][nt] = (floatx4){0.f, 0.f, 0.f, 0.f};

  for (int kc = 0; kc < 5; kc++) {
    bf16x8 a0 = *(const bf16x8*)(ap0 + kc * 32);
    bf16x8 a1 = *(const bf16x8*)(ap1 + kc * 32);
    const ushort_t* wp = Wb + (size_t)(kc * 10) * 1024 + lane * 8;
#pragma unroll
    for (int nt = 0; nt < 10; nt++) {
      bf16x8 bh = *(const bf16x8*)(wp);
      bf16x8 bl = *(const bf16x8*)(wp + 512);
      acc[0][nt] = __builtin_amdgcn_mfma_f32_16x16x32_bf16(a0, bh, acc[0][nt], 0, 0, 0);
      acc[1][nt] = __builtin_amdgcn_mfma_f32_16x16x32_bf16(a1, bh, acc[1][nt], 0, 0, 0);
      acc[0][nt] = __builtin_amdgcn_mfma_f32_16x16x32_bf16(a0, bl, acc[0][nt], 0, 0, 0);
      acc[1][nt] = __builtin_amdgcn_mfma_f32_16x16x32_bf16(a1, bl, acc[1][nt], 0, 0, 0);
      wp += 1024;
    }
  }

  float sn[2][4];
  if (LAYER) {
#pragma unroll
    for (int s = 0; s < 2; s++)
#pragma unroll
      for (int r = 0; r < 4; r++) sn[s][r] = snorm[min(m0 + s * 16 + quad * 4 + r, N_NODES - 1)];
  }
#pragma unroll
  for (int nt = 0; nt < 10; nt++) {
    int c = nt * 16 + l16;
    if (c < DIM) {
      float b = bias[c];
      float ssum = 0.f, ssq = 0.f;
#pragma unroll
      for (int s = 0; s < 2; s++) {
#pragma unroll
        for (int r = 0; r < 4; r++) {
          int row = m0 + s * 16 + quad * 4 + r;
          if (row < N_NODES) {
            float val = acc[s][nt][r] + b;
            if (LAYER) val *= sn[s][r];
            out[(size_t)row * DIM + c] = val;
            if (LAYER) { ssum += val; ssq += val * val; }
          }
        }
      }
      if (LAYER) {
        ssum += __shfl_xor(ssum, 16, 64); ssum += __shfl_xor(ssum, 32, 64);
        ssq  += __shfl_xor(ssq, 16, 64);  ssq  += __shfl_xor(ssq, 32, 64);
        if (quad == 0) {
          atomicAdd(&sred[c], ssum);
          atomicAdd(&sred[DIM + c], ssq);
        }
      }
    }
  }
  if (LAYER) {
    __syncthreads();
    for (int i = threadIdx.x; i < 2 * DIM; i += 256) atomicAdd(&stats[i], sred[i]);
  }
}

// ------- aggregation: one wave per destination node, bf16 gather (pre-scaled hb) -------
// Lanes 0..39 each own 4 columns (uint2 = 4 bf16); fp32 accumulate; write bf16 xb.
__global__ __launch_bounds__(256) void agg_kernel(
    const ushort_t* __restrict__ hb, const int* __restrict__ row_ptr,
    const int* __restrict__ csr, const float* __restrict__ norm_in,
    ushort_t* __restrict__ xb) {
  int wid = threadIdx.x >> 6, lane = threadIdx.x & 63;
  int v = blockIdx.x * 4 + wid;
  if (v >= N_NODES) return;
  int e0 = row_ptr[v], e1 = row_ptr[v + 1];
  bool act = lane < 40;
  int col8 = lane * 4;  // ushort offset within row
  float a0 = 0.f, a1 = 0.f, a2 = 0.f, a3 = 0.f;
  float b0 = 0.f, b1 = 0.f, b2 = 0.f, b3 = 0.f;
  int e = e0;
  for (; e + 1 < e1; e += 2) {
    int s0 = csr[e], s1 = csr[e + 1];
    if (act) {
      uint2 u0 = *(const uint2*)(hb + (size_t)s0 * APAD + col8);
      uint2 u1 = *(const uint2*)(hb + (size_t)s1 * APAD + col8);
      a0 += bflo(u0.x); a1 += bfhi(u0.x); a2 += bflo(u0.y); a3 += bfhi(u0.y);
      b0 += bflo(u1.x); b1 += bfhi(u1.x); b2 += bflo(u1.y); b3 += bfhi(u1.y);
    }
  }
  if (e < e1) {
    int s0 = csr[e];
    if (act) {
      uint2 u0 = *(const uint2*)(hb + (size_t)s0 * APAD + col8);
      a0 += bflo(u0.x); a1 += bfhi(u0.x); a2 += bflo(u0.y); a3 += bfhi(u0.y);
    }
  }
  if (act) {
    float ni = norm_in[v];
    uint2 o;
    o.x = pack2bf((a0 + b0) * ni, (a1 + b1) * ni);
    o.y = pack2bf((a2 + b2) * ni, (a3 + b3) * ni);
    *(uint2*)((uint_t*)(xb + (size_t)v * APAD) + lane * 2) = o;
  }
}

// ------- fused BN-prep + BN + ReLU + residual; writes h (fp32) and hb (bf16*norm_out) ---
__global__ __launch_bounds__(256) void bn_kernel(const float* __restrict__ tmp,
                                                 const float* __restrict__ stats,
                                                 const float* __restrict__ gamma,
                                                 const float* __restrict__ beta,
                                                 const float* __restrict__ norm_out,
                                                 float* __restrict__ h,
                                                 ushort_t* __restrict__ hb) {
  __shared__ float2 scs[DIM / 2], shs[DIM / 2];
  int t = threadIdx.x;
  if (t < DIM / 2) {
    int c0 = 2 * t, c1 = c0 + 1;
    float mu0 = stats[c0] * (1.f / N_NODES), mu1 = stats[c1] * (1.f / N_NODES);
    float v0 = stats[DIM + c0] * (1.f / N_NODES) - mu0 * mu0;
    float v1 = stats[DIM + c1] * (1.f / N_NODES) - mu1 * mu1;
    float s0 = gamma[c0] * rsqrtf(v0 + BN_EPS), s1 = gamma[c1] * rsqrtf(v1 + BN_EPS);
    scs[t] = make_float2(s0, s1);
    shs[t] = make_float2(beta[c0] - mu0 * s0, beta[c1] - mu1 * s1);
  }
  __syncthreads();
  int idx = blockIdx.x * 256 + t;
  if (idx >= N_NODES * (DIM / 2)) return;
  int v = idx / (DIM / 2), c2 = idx - v * (DIM / 2);
  float2 tv = *(const float2*)(tmp + (size_t)v * DIM + 2 * c2);
  float2 sc = scs[c2], sh = shs[c2];
  float2* hp = (float2*)(h + (size_t)v * DIM + 2 * c2);
  float2 hv = *hp;
  float x0 = fmaf(tv.x, sc.x, sh.x); x0 = fmaxf(x0, 0.f);
  float x1 = fmaf(tv.y, sc.y, sh.y); x1 = fmaxf(x1, 0.f);
  hv.x += x0; hv.y += x1;
  *hp = hv;
  float no = norm_out[v];
  ((uint_t*)hb)[(size_t)v * (APAD / 2) + c2] = pack2bf(hv.x * no, hv.y * no);
}

// ---------------- layer-3 fused: BN+ReLU+residual -> per-graph sum ----------------
__global__ __launch_bounds__(192) void gsum_kernel(
    const float* __restrict__ tmp, const float* __restrict__ stats,
    const float* __restrict__ gamma, const float* __restrict__ beta,
    const float* __restrict__ h, const int* __restrict__ gids,
    float* __restrict__ hgp) {
  int t = threadIdx.x;
  if (t > DIM) return;
  float sc = 0.f, sh = 0.f;
  if (t < DIM) {
    float mu = stats[t] * (1.f / N_NODES);
    float var = stats[DIM + t] * (1.f / N_NODES) - mu * mu;
    sc = gamma[t] * rsqrtf(var + BN_EPS);
    sh = beta[t] - mu * sc;
  }
  int r0 = blockIdx.x * 64;
  int part = blockIdx.x & (GS_PART - 1);
  float accv = 0.f;
  int g_prev = gids[r0];
  for (int rr = 0; rr < 64; rr++) {
    int r = r0 + rr;
    if (r >= N_NODES) break;
    int g = gids[r];
    if (g != g_prev) {
      atomicAdd(&hgp[(size_t)(part * N_GRAPHS + g_prev) * GS_STRIDE + t], accv);
      accv = 0.f; g_prev = g;
    }
    float val;
    if (t < DIM) {
      float x = fmaf(tmp[(size_t)r * DIM + t], sc, sh);
      x = fmaxf(x, 0.f);
      val = h[(size_t)r * DIM + t] + x;
    } else {
      val = 1.f;
    }
    accv += val;
  }
  atomicAdd(&hgp[(size_t)(part * N_GRAPHS + g_prev) * GS_STRIDE + t], accv);
}

// ---------------- fused mean + MLP readout: one block per graph ----------------
__global__ __launch_bounds__(256) void mlp_kernel(
    const float* __restrict__ hgp,
    const float* __restrict__ W1, const float* __restrict__ b1,
    const float* __restrict__ W2, const float* __restrict__ b2,
    const float* __restrict__ W3, const float* __restrict__ b3,
    float* __restrict__ out) {
  __shared__ float hrow[DIM];
  __shared__ float x1[73];
  __shared__ float x2[36];
  int g = blockIdx.x;
  int t = threadIdx.x;
  if (t < DIM) {
    float s = 0.f, cnt = 0.f;
#pragma unroll
    for (int p = 0; p < GS_PART; p++) {
      const float* row = hgp + (size_t)(p * N_GRAPHS + g) * GS_STRIDE;
      s += row[t];
      cnt += row[DIM];
    }
    hrow[t] = s / cnt;
  }
  __syncthreads();
  if (t < 73) {
    float s = b1[t];
    for (int k = 0; k < DIM; k++) s = fmaf(hrow[k], W1[k * 73 + t], s);
    x1[t] = s > 0.f ? s : 0.f;
  }
  __syncthreads();
  if (t < 36) {
    float s = b2[t];
    for (int k = 0; k < 73; k++) s = fmaf(x1[k], W2[k * 36 + t], s);
    x2[t] = s > 0.f ? s : 0.f;
  }
  __syncthreads();
  if (t < 10) {
    float s = b3[t];
    for (int k = 0; k < 36; k++) s = fmaf(x2[k], W3[k * 10 + t], s);
    out[g * 10 + t] = s;
  }
}

extern "C" void kernel_launch(void* const* d_in, const int* in_sizes, int n_in,
                              void* d_out, int out_size, void* d_ws, size_t ws_size,
                              hipStream_t stream) {
  const float* nodes_feat = (const float*)d_in[0];
  const float* snorm  = (const float*)d_in[1];
  const float* W_emb  = (const float*)d_in[2];
  const float* b_emb  = (const float*)d_in[3];
  const float* Ws     = (const float*)d_in[4];
  const float* bs     = (const float*)d_in[5];
  const float* gammas = (const float*)d_in[6];
  const float* betas  = (const float*)d_in[7];
  const float* W1 = (const float*)d_in[8];
  const float* b1 = (const float*)d_in[9];
  const float* W2 = (const float*)d_in[10];
  const float* b2 = (const float*)d_in[11];
  const float* W3 = (const float*)d_in[12];
  const float* b3 = (const float*)d_in[13];
  const int* src  = (const int*)d_in[14];
  const int* dst  = (const int*)d_in[15];
  const int* gids = (const int*)d_in[16];
  float* out = (float*)d_out;

  char* base = (char*)d_ws;
  size_t off = 0;
  auto alloc = [&](size_t bytes) { void* p = base + off; off += (bytes + 255) & ~size_t(255); return p; };
  float* h    = (float*)alloc((size_t)N_NODES * DIM * 4);
  float* tmp  = (float*)alloc((size_t)N_NODES * DIM * 4);
  ushort_t* xb = (ushort_t*)alloc((size_t)N_NODES * APAD * 2);  // bf16 GEMM input
  ushort_t* hb = (ushort_t*)alloc((size_t)N_NODES * APAD * 2);  // bf16 h * norm_out
  char* zstart = base + off;
  int* deg_out = (int*)alloc(N_NODES * 4);
  int* deg_in  = (int*)alloc(N_NODES * 4);
  int* fill    = (int*)alloc(N_NODES * 4);
  float* stats = (float*)alloc(4 * 2 * DIM * 4);   // per layer: [sum, sumsq]
  float* hgp   = (float*)alloc((size_t)GS_PART * N_GRAPHS * GS_STRIDE * 4);
  size_t zbytes = (size_t)((base + off) - zstart);
  int* row_ptr = (int*)alloc((N_NODES + 1) * 4);
  float* norm_out = (float*)alloc(N_NODES * 4);
  float* norm_in  = (float*)alloc(N_NODES * 4);
  int* csr   = (int*)alloc((size_t)N_EDGES * 4);
  int* bsums = (int*)alloc(128 * 4);
  int* bofs  = (int*)alloc(128 * 4);
  ushort_t* Wb = (ushort_t*)alloc((size_t)5 * 5 * 10 * 2 * 64 * 8 * 2);

  hipMemsetAsync(zstart, 0, zbytes, stream);

  hist_kernel<<<(N_EDGES + 255) / 256, 256, 0, stream>>>(src, dst, deg_out, deg_in);
  norm_kernel<<<(N_NODES + 255) / 256, 256, 0, stream>>>(deg_out, deg_in, norm_out, norm_in);
  int nb = (N_NODES + 1023) / 1024;
  scan1_kernel<<<nb, 256, 0, stream>>>(deg_in, bsums);
  scan2_kernel<<<1, 64, 0, stream>>>(bsums, bofs, row_ptr, nb);
  scan3_kernel<<<nb, 256, 0, stream>>>(deg_in, bofs, row_ptr);
  csr_fill_kernel<<<(N_EDGES + 255) / 256, 256, 0, stream>>>(src, dst, row_ptr, fill, csr);
  wtrans_kernel<<<(5 * 5 * 10 * 64 * 8 + 255) / 256, 256, 0, stream>>>(W_emb, Ws, Wb);
  nf2bf_kernel<<<(N_NODES * (APAD / 2) + 255) / 256, 256, 0, stream>>>(nodes_feat, xb);

  const int GB = (N_NODES + 127) / 128;
  const size_t WM = (size_t)5 * 10 * 2 * 64 * 8;  // Wb elems per matrix

  gemm_kernel<false><<<GB, 256, 0, stream>>>(xb, Wb, b_emb, nullptr, h, nullptr);
  h2hb_kernel<<<(N_NODES * (APAD / 2) + 255) / 256, 256, 0, stream>>>(h, norm_out, hb);

  for (int l = 0; l < 4; l++) {
    float* st = stats + l * 2 * DIM;
    agg_kernel<<<(N_NODES + 3) / 4, 256, 0, stream>>>(hb, row_ptr, csr, norm_in, xb);
    gemm_kernel<true><<<GB, 256, 0, stream>>>(xb, Wb + (size_t)(l + 1) * WM,
                                              bs + l * DIM, snorm, tmp, st);
    if (l < 3) {
      bn_kernel<<<(N_NODES * (DIM / 2) + 255) / 256, 256, 0, stream>>>(
          tmp, st, gammas + l * DIM, betas + l * DIM, norm_out, h, hb);
    } else {
      gsum_kernel<<<(N_NODES + 63) / 64, 192, 0, stream>>>(
          tmp, st, gammas + l * DIM, betas + l * DIM, h, gids, hgp);
    }
  }

  mlp_kernel<<<N_GRAPHS, 256, 0, stream>>>(hgp, W1, b1, W2, b2, W3, b3, out);
}